// Round 1
// baseline (13995.403 us; speedup 1.0000x reference)
//
#include <hip/hip_runtime.h>
#include <math.h>

#define N_NODES 50000
#define E_EDGES 400000
#define E2 (E_EDGES + N_NODES)
#define NEG_SLOPE 0.2f

static inline int cdiv(long a, int b) { return (int)((a + b - 1) / b); }

// ---------- helpers ----------
__device__ __forceinline__ unsigned enc_f32(float f) {
    unsigned u = __float_as_uint(f);
    return (u & 0x80000000u) ? ~u : (u | 0x80000000u);
}
__device__ __forceinline__ float dec_f32(unsigned e) {
    unsigned u = (e & 0x80000000u) ? (e & 0x7FFFFFFFu) : ~e;
    return __uint_as_float(u);
}
__device__ __forceinline__ void edge_ends(const int* __restrict__ ei, int e, int& src, int& dst) {
    if (e < E_EDGES) { src = ei[e]; dst = ei[E_EDGES + e]; }
    else             { src = dst = e - E_EDGES; }
}

// ---------- dense GEMM: out[i,j] = sum_k x[i,k] * W[k,j] ----------
__global__ void k_gemm(const float* __restrict__ x, const float* __restrict__ W,
                       float* __restrict__ out, int n, int K, int F) {
    int idx = blockIdx.x * blockDim.x + threadIdx.x;
    if (idx >= n * F) return;
    int j = idx % F, i = idx / F;
    const float* xr = x + (size_t)i * K;
    float acc = 0.f;
    for (int k = 0; k < K; ++k) acc += xr[k] * W[(size_t)k * F + j];
    out[idx] = acc;
}

// ---------- per-node attention coefficients ----------
__global__ void k_coef(const float* __restrict__ h, const float* __restrict__ a_src,
                       const float* __restrict__ a_dst, float* __restrict__ es,
                       float* __restrict__ ed, int n, int H, int C) {
    int idx = blockIdx.x * blockDim.x + threadIdx.x;
    if (idx >= n * H) return;
    int hh = idx % H;
    const float* hr = h + (size_t)idx * C;
    float s1 = 0.f, s2 = 0.f;
    for (int c = 0; c < C; ++c) {
        float v = hr[c];
        s1 += v * a_src[hh * C + c];
        s2 += v * a_dst[hh * C + c];
    }
    es[idx] = s1;
    ed[idx] = s2;
}

// ---------- edge pass 1: segment max ----------
__global__ void k_edge_max(const int* __restrict__ ei, const float* __restrict__ es,
                           const float* __restrict__ ed, unsigned* __restrict__ menc, int H) {
    int idx = blockIdx.x * blockDim.x + threadIdx.x;
    if (idx >= E2 * H) return;
    int hh = idx % H, e = idx / H;
    int src, dst; edge_ends(ei, e, src, dst);
    float v = es[src * H + hh] + ed[dst * H + hh];
    v = (v > 0.f) ? v : NEG_SLOPE * v;
    atomicMax(&menc[dst * H + hh], enc_f32(v));
}

// ---------- edge pass 2: segment sum of exp ----------
__global__ void k_edge_sum(const int* __restrict__ ei, const float* __restrict__ es,
                           const float* __restrict__ ed, const unsigned* __restrict__ menc,
                           float* __restrict__ ssum, int H) {
    int idx = blockIdx.x * blockDim.x + threadIdx.x;
    if (idx >= E2 * H) return;
    int hh = idx % H, e = idx / H;
    int src, dst; edge_ends(ei, e, src, dst);
    float v = es[src * H + hh] + ed[dst * H + hh];
    v = (v > 0.f) ? v : NEG_SLOPE * v;
    float m = dec_f32(menc[dst * H + hh]);
    atomicAdd(&ssum[dst * H + hh], expf(v - m));
}

// ---------- edge pass 3: weighted scatter-aggregate ----------
__global__ void k_edge_agg(const int* __restrict__ ei, const float* __restrict__ es,
                           const float* __restrict__ ed, const unsigned* __restrict__ menc,
                           const float* __restrict__ ssum, const float* __restrict__ h,
                           float* __restrict__ agg, int H, int C) {
    int idx = blockIdx.x * blockDim.x + threadIdx.x;
    if (idx >= E2 * H) return;
    int hh = idx % H, e = idx / H;
    int src, dst; edge_ends(ei, e, src, dst);
    float v = es[src * H + hh] + ed[dst * H + hh];
    v = (v > 0.f) ? v : NEG_SLOPE * v;
    float m = dec_f32(menc[dst * H + hh]);
    float alpha = expf(v - m) / ssum[dst * H + hh];
    const float* hs = h + ((size_t)src * H + hh) * C;
    float* ad = agg + ((size_t)dst * H + hh) * C;
    for (int c = 0; c < C; ++c) atomicAdd(&ad[c], hs[c] * alpha);
}

// ---------- bias + optional ELU ----------
__global__ void k_bias_act(const float* __restrict__ agg, const float* __restrict__ b,
                           float* __restrict__ out, int n, int F, int do_elu) {
    int idx = blockIdx.x * blockDim.x + threadIdx.x;
    if (idx >= n * F) return;
    int j = idx % F;
    float v = agg[idx] + b[j];
    if (do_elu) v = (v > 0.f) ? v : expm1f(v);
    out[idx] = v;
}

// ---------- final mean + b3 ----------
__global__ void k_mean(const float* __restrict__ v, const float* __restrict__ b3,
                       float* __restrict__ out, int n) {
    __shared__ float sdata[256];
    float local = 0.f;
    for (int i = blockIdx.x * blockDim.x + threadIdx.x; i < n; i += gridDim.x * blockDim.x)
        local += v[i];
    sdata[threadIdx.x] = local;
    __syncthreads();
    for (int sft = 128; sft > 0; sft >>= 1) {
        if (threadIdx.x < sft) sdata[threadIdx.x] += sdata[threadIdx.x + sft];
        __syncthreads();
    }
    if (threadIdx.x == 0) {
        float add = sdata[0] / (float)n;
        if (blockIdx.x == 0) add += b3[0];
        atomicAdd(out, add);
    }
}

extern "C" void kernel_launch(void* const* d_in, const int* in_sizes, int n_in,
                              void* d_out, int out_size, void* d_ws, size_t ws_size,
                              hipStream_t stream) {
    const float* x      = (const float*)d_in[0];
    const float* W1     = (const float*)d_in[1];
    const float* a_src1 = (const float*)d_in[2];
    const float* a_dst1 = (const float*)d_in[3];
    const float* b1     = (const float*)d_in[4];
    const float* W2     = (const float*)d_in[5];
    const float* a_src2 = (const float*)d_in[6];
    const float* a_dst2 = (const float*)d_in[7];
    const float* b2     = (const float*)d_in[8];
    const float* W3     = (const float*)d_in[9];
    const float* a_src3 = (const float*)d_in[10];
    const float* a_dst3 = (const float*)d_in[11];
    const float* b3     = (const float*)d_in[12];
    const int*   ei     = (const int*)d_in[13];
    float* out = (float*)d_out;

    const int BS = 256;
    const size_t N = N_NODES;

    // workspace layout (floats)
    float* ws      = (float*)d_ws;
    float* h_buf   = ws;                       // N*512
    float* agg_buf = h_buf + N * 512;          // N*512 (also reused for layer2/3 buffers)
    float* es_buf  = agg_buf + N * 512;        // N*4
    float* ed_buf  = es_buf + N * 4;           // N*4
    unsigned* m_buf = (unsigned*)(ed_buf + N * 4); // N*4
    float* s_buf   = (float*)(m_buf + N * 4);  // N*4

    // ---------------- Layer 1: H=4, C=128 ----------------
    {
        const int H = 4, C = 128, F = 512;
        k_gemm<<<cdiv((long)N * F, BS), BS, 0, stream>>>(x, W1, h_buf, N_NODES, 21, F);
        k_coef<<<cdiv((long)N * H, BS), BS, 0, stream>>>(h_buf, a_src1, a_dst1, es_buf, ed_buf, N_NODES, H, C);
        hipMemsetAsync(m_buf, 0, N * H * 4, stream);
        hipMemsetAsync(s_buf, 0, N * H * 4, stream);
        hipMemsetAsync(agg_buf, 0, N * F * 4, stream);
        k_edge_max<<<cdiv((long)E2 * H, BS), BS, 0, stream>>>(ei, es_buf, ed_buf, m_buf, H);
        k_edge_sum<<<cdiv((long)E2 * H, BS), BS, 0, stream>>>(ei, es_buf, ed_buf, m_buf, s_buf, H);
        k_edge_agg<<<cdiv((long)E2 * H, BS), BS, 0, stream>>>(ei, es_buf, ed_buf, m_buf, s_buf, h_buf, agg_buf, H, C);
        k_bias_act<<<cdiv((long)N * F, BS), BS, 0, stream>>>(agg_buf, b1, h_buf, N_NODES, F, 1); // out1 -> h_buf
    }

    // ---------------- Layer 2: H=1, C=64 ----------------
    float* h2raw = agg_buf;            // N*64
    float* agg2  = agg_buf + N * 64;   // N*64
    {
        const int H = 1, C = 64, F = 64;
        k_gemm<<<cdiv((long)N * F, BS), BS, 0, stream>>>(h_buf, W2, h2raw, N_NODES, 512, F);
        k_coef<<<cdiv((long)N * H, BS), BS, 0, stream>>>(h2raw, a_src2, a_dst2, es_buf, ed_buf, N_NODES, H, C);
        hipMemsetAsync(m_buf, 0, N * H * 4, stream);
        hipMemsetAsync(s_buf, 0, N * H * 4, stream);
        hipMemsetAsync(agg2, 0, N * F * 4, stream);
        k_edge_max<<<cdiv((long)E2 * H, BS), BS, 0, stream>>>(ei, es_buf, ed_buf, m_buf, H);
        k_edge_sum<<<cdiv((long)E2 * H, BS), BS, 0, stream>>>(ei, es_buf, ed_buf, m_buf, s_buf, H);
        k_edge_agg<<<cdiv((long)E2 * H, BS), BS, 0, stream>>>(ei, es_buf, ed_buf, m_buf, s_buf, h2raw, agg2, H, C);
        k_bias_act<<<cdiv((long)N * F, BS), BS, 0, stream>>>(agg2, b2, h_buf, N_NODES, F, 1); // out2 -> h_buf[0:N*64]
    }

    // ---------------- Layer 3: H=1, C=1 ----------------
    float* h3raw = agg_buf + N * 128;      // N
    float* agg3  = agg_buf + N * 128 + N;  // N
    {
        const int H = 1, C = 1, F = 1;
        k_gemm<<<cdiv((long)N * F, BS), BS, 0, stream>>>(h_buf, W3, h3raw, N_NODES, 64, F);
        k_coef<<<cdiv((long)N * H, BS), BS, 0, stream>>>(h3raw, a_src3, a_dst3, es_buf, ed_buf, N_NODES, H, C);
        hipMemsetAsync(m_buf, 0, N * H * 4, stream);
        hipMemsetAsync(s_buf, 0, N * H * 4, stream);
        hipMemsetAsync(agg3, 0, N * F * 4, stream);
        k_edge_max<<<cdiv((long)E2 * H, BS), BS, 0, stream>>>(ei, es_buf, ed_buf, m_buf, H);
        k_edge_sum<<<cdiv((long)E2 * H, BS), BS, 0, stream>>>(ei, es_buf, ed_buf, m_buf, s_buf, H);
        k_edge_agg<<<cdiv((long)E2 * H, BS), BS, 0, stream>>>(ei, es_buf, ed_buf, m_buf, s_buf, h3raw, agg3, H, C);
    }

    hipMemsetAsync(out, 0, sizeof(float), stream);
    k_mean<<<256, 256, 0, stream>>>(agg3, b3, out, N_NODES);
}

// Round 2
// 1384.085 us; speedup vs baseline: 10.1117x; 10.1117x over previous
//
#include <hip/hip_runtime.h>
#include <math.h>

#define N_NODES 50000
#define E_EDGES 400000
#define NEG_SLOPE 0.2f

static inline int cdiv(long a, int b) { return (int)((a + b - 1) / b); }

__device__ __forceinline__ float lrelu(float v) {
    return v > 0.f ? v : NEG_SLOPE * v;
}

// ---------------- CSR build ----------------
__global__ void k_count(const int* __restrict__ ei, int* __restrict__ deg) {
    int e = blockIdx.x * blockDim.x + threadIdx.x;
    if (e >= E_EDGES) return;
    atomicAdd(&deg[ei[E_EDGES + e]], 1);
}

// single-block exclusive scan of deg[0..n) -> row_ptr[0..n]
__global__ void k_scan(const int* __restrict__ deg, int* __restrict__ row_ptr, int n) {
    __shared__ int part[1024];
    int t = threadIdx.x;
    int chunk = (n + 1023) / 1024;
    int lo = t * chunk, hi = min(lo + chunk, n);
    int s = 0;
    for (int i = lo; i < hi; ++i) s += deg[i];
    part[t] = s;
    __syncthreads();
    for (int off = 1; off < 1024; off <<= 1) {
        int v = (t >= off) ? part[t - off] : 0;
        __syncthreads();
        part[t] += v;
        __syncthreads();
    }
    int base = (t == 0) ? 0 : part[t - 1];
    for (int i = lo; i < hi; ++i) {
        row_ptr[i] = base;
        base += deg[i];
    }
    if (t == 1023) row_ptr[n] = part[1023];
}

__global__ void k_scatter(const int* __restrict__ ei, const int* __restrict__ row_ptr,
                          int* __restrict__ pos, int* __restrict__ csr_src) {
    int e = blockIdx.x * blockDim.x + threadIdx.x;
    if (e >= E_EDGES) return;
    int src = ei[e], dst = ei[E_EDGES + e];
    int p = atomicAdd(&pos[dst], 1);
    csr_src[row_ptr[dst] + p] = src;
}

// ---------------- dense GEMM: out[i,j] = sum_k x[i,k]*W[k,j] ----------------
__global__ void k_gemm(const float* __restrict__ x, const float* __restrict__ W,
                       float* __restrict__ out, int n, int K, int F) {
    int idx = blockIdx.x * blockDim.x + threadIdx.x;
    if (idx >= n * F) return;
    int j = idx % F, i = idx / F;
    const float* xr = x + (size_t)i * K;
    float acc = 0.f;
    for (int k = 0; k < K; ++k) acc += xr[k] * W[(size_t)k * F + j];
    out[idx] = acc;
}

// ---------------- per-node attention coefficients ----------------
__global__ void k_coef(const float* __restrict__ h, const float* __restrict__ a_src,
                       const float* __restrict__ a_dst, float* __restrict__ es,
                       float* __restrict__ ed, int n, int H, int C) {
    int idx = blockIdx.x * blockDim.x + threadIdx.x;
    if (idx >= n * H) return;
    int hh = idx % H;
    const float* hr = h + (size_t)idx * C;
    float s1 = 0.f, s2 = 0.f;
    for (int c = 0; c < C; ++c) {
        float v = hr[c];
        s1 += v * a_src[hh * C + c];
        s2 += v * a_dst[hh * C + c];
    }
    es[idx] = s1;
    ed[idx] = s2;
}

// ---------------- fused GAT edge phase: wave per (dst, head) ----------------
// softmax(max, sum) + weighted gather-aggregate + bias + optional ELU
template <int H, int C>
__global__ void k_gat_edge(const int* __restrict__ row_ptr, const int* __restrict__ csr_src,
                           const float* __restrict__ h, const float* __restrict__ es,
                           const float* __restrict__ ed, const float* __restrict__ b,
                           float* __restrict__ out, int do_elu) {
    int wid = (blockIdx.x * blockDim.x + threadIdx.x) >> 6;
    int lane = threadIdx.x & 63;
    if (wid >= N_NODES * H) return;
    int dst = wid / H, hh = wid % H;
    int beg = row_ptr[dst], end = row_ptr[dst + 1];
    float edd = ed[dst * H + hh];

    float self_v = lrelu(es[dst * H + hh] + edd);

    // pass 1: max over in-edges (distributed over lanes)
    float m = self_v;
    for (int k = beg + lane; k < end; k += 64) {
        float v = lrelu(es[csr_src[k] * H + hh] + edd);
        m = fmaxf(m, v);
    }
    #pragma unroll
    for (int off = 32; off; off >>= 1) m = fmaxf(m, __shfl_xor(m, off, 64));

    // pass 2: sum of exp
    float s = 0.f;
    for (int k = beg + lane; k < end; k += 64) {
        float v = lrelu(es[csr_src[k] * H + hh] + edd);
        s += expf(v - m);
    }
    #pragma unroll
    for (int off = 32; off; off >>= 1) s += __shfl_xor(s, off, 64);
    float p_self = expf(self_v - m);
    s += p_self;
    float inv_s = 1.f / s;

    // pass 3: aggregate (lanes over channels, wave walks edges together)
    constexpr int CPL = (C + 63) / 64;
    float acc[CPL];
    const float* hd = h + ((size_t)dst * H + hh) * C;
    float a_self = p_self * inv_s;
    #pragma unroll
    for (int q = 0; q < CPL; ++q) {
        int c = lane + 64 * q;
        acc[q] = (c < C) ? a_self * hd[c] : 0.f;
    }
    for (int k = beg; k < end; ++k) {
        int src = csr_src[k];  // wave-uniform load per iteration
        float v = lrelu(es[src * H + hh] + edd);
        float alpha = expf(v - m) * inv_s;
        const float* hs = h + ((size_t)src * H + hh) * C;
        #pragma unroll
        for (int q = 0; q < CPL; ++q) {
            int c = lane + 64 * q;
            if (c < C) acc[q] += alpha * hs[c];
        }
    }

    // epilogue: bias + ELU, direct write
    #pragma unroll
    for (int q = 0; q < CPL; ++q) {
        int c = lane + 64 * q;
        if (c < C) {
            float vv = acc[q] + b[hh * C + c];
            if (do_elu) vv = vv > 0.f ? vv : expm1f(vv);
            out[((size_t)dst * H + hh) * C + c] = vv;
        }
    }
}

// ---------------- layer 3 (H=1, C=1): one thread per dst ----------------
__global__ void k_gat_edge_c1(const int* __restrict__ row_ptr, const int* __restrict__ csr_src,
                              const float* __restrict__ h, const float* __restrict__ es,
                              const float* __restrict__ ed, float* __restrict__ out) {
    int dst = blockIdx.x * blockDim.x + threadIdx.x;
    if (dst >= N_NODES) return;
    int beg = row_ptr[dst], end = row_ptr[dst + 1];
    float edd = ed[dst];
    float self_v = lrelu(es[dst] + edd);
    float m = self_v;
    for (int k = beg; k < end; ++k) m = fmaxf(m, lrelu(es[csr_src[k]] + edd));
    float p = expf(self_v - m);
    float s = p;
    float acc = p * h[dst];
    for (int k = beg; k < end; ++k) {
        int src = csr_src[k];
        float pv = expf(lrelu(es[src] + edd) - m);
        s += pv;
        acc += pv * h[src];
    }
    out[dst] = acc / s;
}

// ---------------- final mean + b3 ----------------
__global__ void k_mean(const float* __restrict__ v, const float* __restrict__ b3,
                       float* __restrict__ out, int n) {
    __shared__ float sdata[256];
    float local = 0.f;
    for (int i = blockIdx.x * blockDim.x + threadIdx.x; i < n; i += gridDim.x * blockDim.x)
        local += v[i];
    sdata[threadIdx.x] = local;
    __syncthreads();
    for (int sft = 128; sft > 0; sft >>= 1) {
        if (threadIdx.x < sft) sdata[threadIdx.x] += sdata[threadIdx.x + sft];
        __syncthreads();
    }
    if (threadIdx.x == 0) {
        float add = sdata[0] / (float)n;
        if (blockIdx.x == 0) add += b3[0];
        atomicAdd(out, add);
    }
}

extern "C" void kernel_launch(void* const* d_in, const int* in_sizes, int n_in,
                              void* d_out, int out_size, void* d_ws, size_t ws_size,
                              hipStream_t stream) {
    const float* x      = (const float*)d_in[0];
    const float* W1     = (const float*)d_in[1];
    const float* a_src1 = (const float*)d_in[2];
    const float* a_dst1 = (const float*)d_in[3];
    const float* b1     = (const float*)d_in[4];
    const float* W2     = (const float*)d_in[5];
    const float* a_src2 = (const float*)d_in[6];
    const float* a_dst2 = (const float*)d_in[7];
    const float* b2     = (const float*)d_in[8];
    const float* W3     = (const float*)d_in[9];
    const float* a_src3 = (const float*)d_in[10];
    const float* a_dst3 = (const float*)d_in[11];
    const float* b3     = (const float*)d_in[12];
    const int*   ei     = (const int*)d_in[13];
    float* out = (float*)d_out;

    const int BS = 256;
    const size_t N = N_NODES;

    // workspace layout
    float* ws      = (float*)d_ws;
    float* h_buf   = ws;                  // N*512 (h1; later h2raw/out2/h3raw/out3)
    float* o_buf   = h_buf + N * 512;     // N*512 (out1)
    float* es_buf  = o_buf + N * 512;     // N*4
    float* ed_buf  = es_buf + N * 4;      // N*4
    int*   deg     = (int*)(ed_buf + N * 4); // N (also reused as scatter pos)
    int*   row_ptr = deg + N;             // N+1
    int*   csr_src = row_ptr + N + 1;     // E_EDGES

    // ---------------- CSR build (shared by all 3 layers) ----------------
    hipMemsetAsync(deg, 0, N * sizeof(int), stream);
    k_count<<<cdiv(E_EDGES, BS), BS, 0, stream>>>(ei, deg);
    k_scan<<<1, 1024, 0, stream>>>(deg, row_ptr, N_NODES);
    hipMemsetAsync(deg, 0, N * sizeof(int), stream);  // reuse as pos
    k_scatter<<<cdiv(E_EDGES, BS), BS, 0, stream>>>(ei, row_ptr, deg, csr_src);

    // ---------------- Layer 1: H=4, C=128 ----------------
    {
        const int H = 4, C = 128, F = 512;
        k_gemm<<<cdiv((long)N * F, BS), BS, 0, stream>>>(x, W1, h_buf, N_NODES, 21, F);
        k_coef<<<cdiv((long)N * H, BS), BS, 0, stream>>>(h_buf, a_src1, a_dst1, es_buf, ed_buf, N_NODES, H, C);
        long thr = (long)N * H * 64;
        k_gat_edge<4, 128><<<cdiv(thr, BS), BS, 0, stream>>>(row_ptr, csr_src, h_buf, es_buf, ed_buf, b1, o_buf, 1);
    }

    // ---------------- Layer 2: H=1, C=64 ----------------
    float* h2raw = h_buf;            // N*64 (h1 dead after layer-1 edge kernel)
    float* out2  = h_buf + N * 64;   // N*64
    {
        const int H = 1, C = 64, F = 64;
        k_gemm<<<cdiv((long)N * F, BS), BS, 0, stream>>>(o_buf, W2, h2raw, N_NODES, 512, F);
        k_coef<<<cdiv((long)N * H, BS), BS, 0, stream>>>(h2raw, a_src2, a_dst2, es_buf, ed_buf, N_NODES, H, C);
        long thr = (long)N * H * 64;
        k_gat_edge<1, 64><<<cdiv(thr, BS), BS, 0, stream>>>(row_ptr, csr_src, h2raw, es_buf, ed_buf, b2, out2, 1);
    }

    // ---------------- Layer 3: H=1, C=1 ----------------
    float* h3raw = h_buf + N * 128;       // N
    float* out3  = h_buf + N * 128 + N;   // N
    {
        k_gemm<<<cdiv((long)N, BS), BS, 0, stream>>>(out2, W3, h3raw, N_NODES, 64, 1);
        k_coef<<<cdiv((long)N, BS), BS, 0, stream>>>(h3raw, a_src3, a_dst3, es_buf, ed_buf, N_NODES, 1, 1);
        k_gat_edge_c1<<<cdiv((long)N, BS), BS, 0, stream>>>(row_ptr, csr_src, h3raw, es_buf, ed_buf, out3);
    }

    hipMemsetAsync(out, 0, sizeof(float), stream);
    k_mean<<<256, 256, 0, stream>>>(out3, b3, out, N_NODES);
}

// Round 3
// 535.674 us; speedup vs baseline: 26.1267x; 2.5838x over previous
//
#include <hip/hip_runtime.h>
#include <math.h>

#define N_NODES 50000
#define E_EDGES 400000
#define NEG_SLOPE 0.2f

static inline int cdiv(long a, int b) { return (int)((a + b - 1) / b); }

__device__ __forceinline__ float lrelu(float v) {
    return v > 0.f ? v : NEG_SLOPE * v;
}

__device__ __forceinline__ float wave_red_sum64(float v) {
    #pragma unroll
    for (int off = 32; off; off >>= 1) v += __shfl_xor(v, off, 64);
    return v;
}

// ---------------- CSR build ----------------
__global__ void k_count(const int* __restrict__ ei, int* __restrict__ deg) {
    int e = blockIdx.x * blockDim.x + threadIdx.x;
    if (e >= E_EDGES) return;
    atomicAdd(&deg[ei[E_EDGES + e]], 1);
}

__global__ void k_scan(const int* __restrict__ deg, int* __restrict__ row_ptr, int n) {
    __shared__ int part[1024];
    int t = threadIdx.x;
    int chunk = (n + 1023) / 1024;
    int lo = t * chunk, hi = min(lo + chunk, n);
    int s = 0;
    for (int i = lo; i < hi; ++i) s += deg[i];
    part[t] = s;
    __syncthreads();
    for (int off = 1; off < 1024; off <<= 1) {
        int v = (t >= off) ? part[t - off] : 0;
        __syncthreads();
        part[t] += v;
        __syncthreads();
    }
    int base = (t == 0) ? 0 : part[t - 1];
    for (int i = lo; i < hi; ++i) {
        row_ptr[i] = base;
        base += deg[i];
    }
    if (t == 1023) row_ptr[n] = part[1023];
}

__global__ void k_scatter(const int* __restrict__ ei, const int* __restrict__ row_ptr,
                          int* __restrict__ pos, int* __restrict__ csr_src) {
    int e = blockIdx.x * blockDim.x + threadIdx.x;
    if (e >= E_EDGES) return;
    int src = ei[e], dst = ei[E_EDGES + e];
    int p = atomicAdd(&pos[dst], 1);
    csr_src[row_ptr[dst] + p] = src;
}

// ---------------- Layer 1: fused GEMM (x@W1) + es/ed coefficients ----------------
// x: [N,21], W1: [21,512] -> h: [N,512]; es/ed: [N,4]
// block = 256 threads, handles 16 rows; thread t covers cols {2t, 2t+1}; wave w == head w.
__global__ void k_l1_gemm_coef(const float* __restrict__ x, const float* __restrict__ W1,
                               const float* __restrict__ a_src, const float* __restrict__ a_dst,
                               float* __restrict__ h, float* __restrict__ es, float* __restrict__ ed) {
    const int t = threadIdx.x;
    const int lane = t & 63;
    const int hh = t >> 6;               // wave index == head
    const int row0 = blockIdx.x * 16;
    const int c = 2 * t;                 // column pair start

    float2 wreg[21];
    #pragma unroll
    for (int k = 0; k < 21; ++k)
        wreg[k] = *(const float2*)&W1[k * 512 + c];

    const int cih = c & 127;             // col within head
    float2 as = *(const float2*)&a_src[hh * 128 + cih];
    float2 ad = *(const float2*)&a_dst[hh * 128 + cih];

    for (int r = 0; r < 16; ++r) {
        const int row = row0 + r;
        const float* xr = x + (size_t)row * 21;
        float2 acc = {0.f, 0.f};
        #pragma unroll
        for (int k = 0; k < 21; ++k) {
            float xv = xr[k];            // block-uniform -> scalar load
            acc.x += xv * wreg[k].x;
            acc.y += xv * wreg[k].y;
        }
        *(float2*)&h[(size_t)row * 512 + c] = acc;
        float p1 = acc.x * as.x + acc.y * as.y;
        float p2 = acc.x * ad.x + acc.y * ad.y;
        p1 = wave_red_sum64(p1);
        p2 = wave_red_sum64(p2);
        if (lane == 0) {
            es[row * 4 + hh] = p1;
            ed[row * 4 + hh] = p2;
        }
    }
}

// ---------------- Layer 2: tiled GEMM (out1@W2) + es/ed ----------------
// A: [N,512], B(W2): [512,64] -> C(h2): [N,64]; es/ed: [N]
// BM=64, BN=64(full), BK=64; 256 threads; thread (tr=t/16, tc=t%16) computes 4x4.
__global__ void k_l2_gemm_coef(const float* __restrict__ A, const float* __restrict__ B,
                               const float* __restrict__ a_src, const float* __restrict__ a_dst,
                               float* __restrict__ C, float* __restrict__ es, float* __restrict__ ed) {
    __shared__ float AT[64][65];   // transposed A-tile: AT[kk][r]
    __shared__ float Bs[64][64];

    const int t = threadIdx.x;
    const int tr = t >> 4, tc = t & 15;
    const int row0 = blockIdx.x * 64;

    float acc[4][4];
    #pragma unroll
    for (int r = 0; r < 4; ++r)
        #pragma unroll
        for (int cc = 0; cc < 4; ++cc) acc[r][cc] = 0.f;

    for (int k0 = 0; k0 < 512; k0 += 64) {
        // stage A (transposed), 1024 float4 slots
        #pragma unroll
        for (int i = 0; i < 4; ++i) {
            int f = i * 256 + t;
            int row = f >> 4, c4 = f & 15;
            int grow = row0 + row;
            float4 v = {0.f, 0.f, 0.f, 0.f};
            if (grow < N_NODES)
                v = *(const float4*)&A[(size_t)grow * 512 + k0 + c4 * 4];
            AT[c4 * 4 + 0][row] = v.x;
            AT[c4 * 4 + 1][row] = v.y;
            AT[c4 * 4 + 2][row] = v.z;
            AT[c4 * 4 + 3][row] = v.w;
        }
        // stage B
        #pragma unroll
        for (int i = 0; i < 4; ++i) {
            int f = i * 256 + t;
            int row = f >> 4, c4 = f & 15;
            *(float4*)&Bs[row][c4 * 4] = *(const float4*)&B[(size_t)(k0 + row) * 64 + c4 * 4];
        }
        __syncthreads();
        #pragma unroll 8
        for (int kk = 0; kk < 64; ++kk) {
            float4 a4 = *(const float4*)&AT[kk][tr * 4];
            float4 b4 = *(const float4*)&Bs[kk][tc * 4];
            const float av[4] = {a4.x, a4.y, a4.z, a4.w};
            const float bv[4] = {b4.x, b4.y, b4.z, b4.w};
            #pragma unroll
            for (int r = 0; r < 4; ++r)
                #pragma unroll
                for (int cc = 0; cc < 4; ++cc)
                    acc[r][cc] += av[r] * bv[cc];
        }
        __syncthreads();
    }

    // epilogue: write C + fused coef reduction (16 lanes per row)
    float4 as4 = *(const float4*)&a_src[tc * 4];
    float4 ad4 = *(const float4*)&a_dst[tc * 4];
    #pragma unroll
    for (int r = 0; r < 4; ++r) {
        int grow = row0 + tr * 4 + r;
        float4 cv = {acc[r][0], acc[r][1], acc[r][2], acc[r][3]};
        float p1 = cv.x * as4.x + cv.y * as4.y + cv.z * as4.z + cv.w * as4.w;
        float p2 = cv.x * ad4.x + cv.y * ad4.y + cv.z * ad4.z + cv.w * ad4.w;
        #pragma unroll
        for (int off = 8; off; off >>= 1) {
            p1 += __shfl_xor(p1, off, 64);
            p2 += __shfl_xor(p2, off, 64);
        }
        if (grow < N_NODES) {
            *(float4*)&C[(size_t)grow * 64 + tc * 4] = cv;
            if (tc == 0) { es[grow] = p1; ed[grow] = p2; }
        }
    }
}

// ---------------- Layer 3: wave-per-node dot (out2@W3) + es/ed ----------------
__global__ void k_l3_gemm_coef(const float* __restrict__ A, const float* __restrict__ W3,
                               const float* __restrict__ a_src, const float* __restrict__ a_dst,
                               float* __restrict__ h3, float* __restrict__ es, float* __restrict__ ed) {
    int gid = blockIdx.x * blockDim.x + threadIdx.x;
    int node = gid >> 6, lane = gid & 63;
    if (node >= N_NODES) return;
    float v = A[(size_t)node * 64 + lane] * W3[lane];
    v = wave_red_sum64(v);
    if (lane == 0) {
        h3[node] = v;
        es[node] = v * a_src[0];
        ed[node] = v * a_dst[0];
    }
}

// ---------------- fused GAT edge phase: wave per (dst, head) ----------------
template <int H, int C>
__global__ void k_gat_edge(const int* __restrict__ row_ptr, const int* __restrict__ csr_src,
                           const float* __restrict__ h, const float* __restrict__ es,
                           const float* __restrict__ ed, const float* __restrict__ b,
                           float* __restrict__ out, int do_elu) {
    int wid = (blockIdx.x * blockDim.x + threadIdx.x) >> 6;
    int lane = threadIdx.x & 63;
    if (wid >= N_NODES * H) return;
    int dst = wid / H, hh = wid % H;
    int beg = row_ptr[dst], end = row_ptr[dst + 1];
    float edd = ed[dst * H + hh];

    float self_v = lrelu(es[dst * H + hh] + edd);

    float m = self_v;
    for (int k = beg + lane; k < end; k += 64) {
        float v = lrelu(es[csr_src[k] * H + hh] + edd);
        m = fmaxf(m, v);
    }
    #pragma unroll
    for (int off = 32; off; off >>= 1) m = fmaxf(m, __shfl_xor(m, off, 64));

    float s = 0.f;
    for (int k = beg + lane; k < end; k += 64) {
        float v = lrelu(es[csr_src[k] * H + hh] + edd);
        s += expf(v - m);
    }
    #pragma unroll
    for (int off = 32; off; off >>= 1) s += __shfl_xor(s, off, 64);
    float p_self = expf(self_v - m);
    s += p_self;
    float inv_s = 1.f / s;

    constexpr int CPL = (C + 63) / 64;
    float acc[CPL];
    const float* hd = h + ((size_t)dst * H + hh) * C;
    float a_self = p_self * inv_s;
    #pragma unroll
    for (int q = 0; q < CPL; ++q) {
        int c = lane + 64 * q;
        acc[q] = (c < C) ? a_self * hd[c] : 0.f;
    }
    for (int k = beg; k < end; ++k) {
        int src = csr_src[k];
        float v = lrelu(es[src * H + hh] + edd);
        float alpha = expf(v - m) * inv_s;
        const float* hs = h + ((size_t)src * H + hh) * C;
        #pragma unroll
        for (int q = 0; q < CPL; ++q) {
            int c = lane + 64 * q;
            if (c < C) acc[q] += alpha * hs[c];
        }
    }

    #pragma unroll
    for (int q = 0; q < CPL; ++q) {
        int c = lane + 64 * q;
        if (c < C) {
            float vv = acc[q] + b[hh * C + c];
            if (do_elu) vv = vv > 0.f ? vv : expm1f(vv);
            out[((size_t)dst * H + hh) * C + c] = vv;
        }
    }
}

// ---------------- layer 3 edge phase (H=1, C=1): thread per dst ----------------
__global__ void k_gat_edge_c1(const int* __restrict__ row_ptr, const int* __restrict__ csr_src,
                              const float* __restrict__ h, const float* __restrict__ es,
                              const float* __restrict__ ed, float* __restrict__ out) {
    int dst = blockIdx.x * blockDim.x + threadIdx.x;
    if (dst >= N_NODES) return;
    int beg = row_ptr[dst], end = row_ptr[dst + 1];
    float edd = ed[dst];
    float self_v = lrelu(es[dst] + edd);
    float m = self_v;
    for (int k = beg; k < end; ++k) m = fmaxf(m, lrelu(es[csr_src[k]] + edd));
    float p = expf(self_v - m);
    float s = p;
    float acc = p * h[dst];
    for (int k = beg; k < end; ++k) {
        int src = csr_src[k];
        float pv = expf(lrelu(es[src] + edd) - m);
        s += pv;
        acc += pv * h[src];
    }
    out[dst] = acc / s;
}

// ---------------- final mean + b3 ----------------
__global__ void k_mean(const float* __restrict__ v, const float* __restrict__ b3,
                       float* __restrict__ out, int n) {
    __shared__ float sdata[256];
    float local = 0.f;
    for (int i = blockIdx.x * blockDim.x + threadIdx.x; i < n; i += gridDim.x * blockDim.x)
        local += v[i];
    sdata[threadIdx.x] = local;
    __syncthreads();
    for (int sft = 128; sft > 0; sft >>= 1) {
        if (threadIdx.x < sft) sdata[threadIdx.x] += sdata[threadIdx.x + sft];
        __syncthreads();
    }
    if (threadIdx.x == 0) {
        float add = sdata[0] / (float)n;
        if (blockIdx.x == 0) add += b3[0];
        atomicAdd(out, add);
    }
}

extern "C" void kernel_launch(void* const* d_in, const int* in_sizes, int n_in,
                              void* d_out, int out_size, void* d_ws, size_t ws_size,
                              hipStream_t stream) {
    const float* x      = (const float*)d_in[0];
    const float* W1     = (const float*)d_in[1];
    const float* a_src1 = (const float*)d_in[2];
    const float* a_dst1 = (const float*)d_in[3];
    const float* b1     = (const float*)d_in[4];
    const float* W2     = (const float*)d_in[5];
    const float* a_src2 = (const float*)d_in[6];
    const float* a_dst2 = (const float*)d_in[7];
    const float* b2     = (const float*)d_in[8];
    const float* W3     = (const float*)d_in[9];
    const float* a_src3 = (const float*)d_in[10];
    const float* a_dst3 = (const float*)d_in[11];
    const float* b3     = (const float*)d_in[12];
    const int*   ei     = (const int*)d_in[13];
    float* out = (float*)d_out;

    const int BS = 256;
    const size_t N = N_NODES;

    float* ws      = (float*)d_ws;
    float* h_buf   = ws;                  // N*512 (h1; later h2raw/out2/h3raw/out3)
    float* o_buf   = h_buf + N * 512;     // N*512 (out1)
    float* es_buf  = o_buf + N * 512;     // N*4
    float* ed_buf  = es_buf + N * 4;      // N*4
    int*   deg     = (int*)(ed_buf + N * 4); // N (reused as scatter pos)
    int*   row_ptr = deg + N;             // N+1
    int*   csr_src = row_ptr + N + 1;     // E_EDGES

    // CSR build (shared by all 3 layers)
    hipMemsetAsync(deg, 0, N * sizeof(int), stream);
    k_count<<<cdiv(E_EDGES, BS), BS, 0, stream>>>(ei, deg);
    k_scan<<<1, 1024, 0, stream>>>(deg, row_ptr, N_NODES);
    hipMemsetAsync(deg, 0, N * sizeof(int), stream);
    k_scatter<<<cdiv(E_EDGES, BS), BS, 0, stream>>>(ei, row_ptr, deg, csr_src);

    // ---------------- Layer 1: H=4, C=128 ----------------
    k_l1_gemm_coef<<<N_NODES / 16, 256, 0, stream>>>(x, W1, a_src1, a_dst1, h_buf, es_buf, ed_buf);
    k_gat_edge<4, 128><<<cdiv((long)N * 4 * 64, BS), BS, 0, stream>>>(row_ptr, csr_src, h_buf, es_buf, ed_buf, b1, o_buf, 1);

    // ---------------- Layer 2: H=1, C=64 ----------------
    float* h2raw = h_buf;            // N*64
    float* out2  = h_buf + N * 64;   // N*64
    k_l2_gemm_coef<<<cdiv(N_NODES, 64), 256, 0, stream>>>(o_buf, W2, a_src2, a_dst2, h2raw, es_buf, ed_buf);
    k_gat_edge<1, 64><<<cdiv((long)N * 64, BS), BS, 0, stream>>>(row_ptr, csr_src, h2raw, es_buf, ed_buf, b2, out2, 1);

    // ---------------- Layer 3: H=1, C=1 ----------------
    float* h3raw = h_buf + N * 128;       // N
    float* out3  = h_buf + N * 128 + N;   // N
    k_l3_gemm_coef<<<cdiv((long)N * 64, BS), BS, 0, stream>>>(out2, W3, a_src3, a_dst3, h3raw, es_buf, ed_buf);
    k_gat_edge_c1<<<cdiv((long)N, BS), BS, 0, stream>>>(row_ptr, csr_src, h3raw, es_buf, ed_buf, out3);

    hipMemsetAsync(out, 0, sizeof(float), stream);
    k_mean<<<256, 256, 0, stream>>>(out3, b3, out, N_NODES);
}

// Round 4
// 437.577 us; speedup vs baseline: 31.9839x; 1.2242x over previous
//
#include <hip/hip_runtime.h>
#include <math.h>

#define N_NODES 50000
#define E_EDGES 400000
#define NEG_SLOPE 0.2f

static inline int cdiv(long a, int b) { return (int)((a + b - 1) / b); }

__device__ __forceinline__ float lrelu(float v) {
    return v > 0.f ? v : NEG_SLOPE * v;
}

__device__ __forceinline__ float wave_red_sum64(float v) {
    #pragma unroll
    for (int off = 32; off; off >>= 1) v += __shfl_xor(v, off, 64);
    return v;
}

// ---------------- CSR build ----------------
__global__ void k_count(const int* __restrict__ ei, int* __restrict__ deg) {
    int e = blockIdx.x * blockDim.x + threadIdx.x;
    if (e >= E_EDGES) return;
    atomicAdd(&deg[ei[E_EDGES + e]], 1);
}

__global__ void k_scan(const int* __restrict__ deg, int* __restrict__ row_ptr, int n) {
    __shared__ int part[1024];
    int t = threadIdx.x;
    int chunk = (n + 1023) / 1024;
    int lo = t * chunk, hi = min(lo + chunk, n);
    int s = 0;
    for (int i = lo; i < hi; ++i) s += deg[i];
    part[t] = s;
    __syncthreads();
    for (int off = 1; off < 1024; off <<= 1) {
        int v = (t >= off) ? part[t - off] : 0;
        __syncthreads();
        part[t] += v;
        __syncthreads();
    }
    int base = (t == 0) ? 0 : part[t - 1];
    for (int i = lo; i < hi; ++i) {
        row_ptr[i] = base;
        base += deg[i];
    }
    if (t == 1023) row_ptr[n] = part[1023];
}

__global__ void k_scatter(const int* __restrict__ ei, const int* __restrict__ row_ptr,
                          int* __restrict__ pos, int* __restrict__ csr_src) {
    int e = blockIdx.x * blockDim.x + threadIdx.x;
    if (e >= E_EDGES) return;
    int src = ei[e], dst = ei[E_EDGES + e];
    int p = atomicAdd(&pos[dst], 1);
    csr_src[row_ptr[dst] + p] = src;
}

// ---------------- Layer 1: fused GEMM (x@W1) + es/ed ----------------
__global__ void k_l1_gemm_coef(const float* __restrict__ x, const float* __restrict__ W1,
                               const float* __restrict__ a_src, const float* __restrict__ a_dst,
                               float* __restrict__ h, float* __restrict__ es, float* __restrict__ ed) {
    const int t = threadIdx.x;
    const int lane = t & 63;
    const int hh = t >> 6;
    const int row0 = blockIdx.x * 16;
    const int c = 2 * t;

    float2 wreg[21];
    #pragma unroll
    for (int k = 0; k < 21; ++k)
        wreg[k] = *(const float2*)&W1[k * 512 + c];

    const int cih = c & 127;
    float2 as = *(const float2*)&a_src[hh * 128 + cih];
    float2 ad = *(const float2*)&a_dst[hh * 128 + cih];

    for (int r = 0; r < 16; ++r) {
        const int row = row0 + r;
        const float* xr = x + (size_t)row * 21;
        float2 acc = {0.f, 0.f};
        #pragma unroll
        for (int k = 0; k < 21; ++k) {
            float xv = xr[k];
            acc.x += xv * wreg[k].x;
            acc.y += xv * wreg[k].y;
        }
        *(float2*)&h[(size_t)row * 512 + c] = acc;
        float p1 = acc.x * as.x + acc.y * as.y;
        float p2 = acc.x * ad.x + acc.y * ad.y;
        p1 = wave_red_sum64(p1);
        p2 = wave_red_sum64(p2);
        if (lane == 0) {
            es[row * 4 + hh] = p1;
            ed[row * 4 + hh] = p2;
        }
    }
}

// ---------------- Layer 2: tiled GEMM (out1@W2) + es/ed ----------------
__global__ void k_l2_gemm_coef(const float* __restrict__ A, const float* __restrict__ B,
                               const float* __restrict__ a_src, const float* __restrict__ a_dst,
                               float* __restrict__ C, float* __restrict__ es, float* __restrict__ ed) {
    __shared__ float AT[64][65];
    __shared__ float Bs[64][64];

    const int t = threadIdx.x;
    const int tr = t >> 4, tc = t & 15;
    const int row0 = blockIdx.x * 64;

    float acc[4][4];
    #pragma unroll
    for (int r = 0; r < 4; ++r)
        #pragma unroll
        for (int cc = 0; cc < 4; ++cc) acc[r][cc] = 0.f;

    for (int k0 = 0; k0 < 512; k0 += 64) {
        #pragma unroll
        for (int i = 0; i < 4; ++i) {
            int f = i * 256 + t;
            int row = f >> 4, c4 = f & 15;
            int grow = row0 + row;
            float4 v = {0.f, 0.f, 0.f, 0.f};
            if (grow < N_NODES)
                v = *(const float4*)&A[(size_t)grow * 512 + k0 + c4 * 4];
            AT[c4 * 4 + 0][row] = v.x;
            AT[c4 * 4 + 1][row] = v.y;
            AT[c4 * 4 + 2][row] = v.z;
            AT[c4 * 4 + 3][row] = v.w;
        }
        #pragma unroll
        for (int i = 0; i < 4; ++i) {
            int f = i * 256 + t;
            int row = f >> 4, c4 = f & 15;
            *(float4*)&Bs[row][c4 * 4] = *(const float4*)&B[(size_t)(k0 + row) * 64 + c4 * 4];
        }
        __syncthreads();
        #pragma unroll 8
        for (int kk = 0; kk < 64; ++kk) {
            float4 a4 = *(const float4*)&AT[kk][tr * 4];
            float4 b4 = *(const float4*)&Bs[kk][tc * 4];
            const float av[4] = {a4.x, a4.y, a4.z, a4.w};
            const float bv[4] = {b4.x, b4.y, b4.z, b4.w};
            #pragma unroll
            for (int r = 0; r < 4; ++r)
                #pragma unroll
                for (int cc = 0; cc < 4; ++cc)
                    acc[r][cc] += av[r] * bv[cc];
        }
        __syncthreads();
    }

    float4 as4 = *(const float4*)&a_src[tc * 4];
    float4 ad4 = *(const float4*)&a_dst[tc * 4];
    #pragma unroll
    for (int r = 0; r < 4; ++r) {
        int grow = row0 + tr * 4 + r;
        float4 cv = {acc[r][0], acc[r][1], acc[r][2], acc[r][3]};
        float p1 = cv.x * as4.x + cv.y * as4.y + cv.z * as4.z + cv.w * as4.w;
        float p2 = cv.x * ad4.x + cv.y * ad4.y + cv.z * ad4.z + cv.w * ad4.w;
        #pragma unroll
        for (int off = 8; off; off >>= 1) {
            p1 += __shfl_xor(p1, off, 64);
            p2 += __shfl_xor(p2, off, 64);
        }
        if (grow < N_NODES) {
            *(float4*)&C[(size_t)grow * 64 + tc * 4] = cv;
            if (tc == 0) { es[grow] = p1; ed[grow] = p2; }
        }
    }
}

// ---------------- Layer 3: wave-per-node dot + es/ed ----------------
__global__ void k_l3_gemm_coef(const float* __restrict__ A, const float* __restrict__ W3,
                               const float* __restrict__ a_src, const float* __restrict__ a_dst,
                               float* __restrict__ h3, float* __restrict__ es, float* __restrict__ ed) {
    int gid = blockIdx.x * blockDim.x + threadIdx.x;
    int node = gid >> 6, lane = gid & 63;
    if (node >= N_NODES) return;
    float v = A[(size_t)node * 64 + lane] * W3[lane];
    v = wave_red_sum64(v);
    if (lane == 0) {
        h3[node] = v;
        es[node] = v * a_src[0];
        ed[node] = v * a_dst[0];
    }
}

// ---------------- Layer 1 edge phase: head-fused, wave per dst ----------------
// lane = hh*16 + sub; channels per lane: [lane*8, lane*8+8) of 512 (all in head hh)
__global__ void k_gat_edge_l1(const int* __restrict__ row_ptr, const int* __restrict__ csr_src,
                              const float* __restrict__ h, const float* __restrict__ es,
                              const float* __restrict__ ed, const float* __restrict__ b,
                              float* __restrict__ out) {
    int wid = (blockIdx.x * blockDim.x + threadIdx.x) >> 6;
    int lane = threadIdx.x & 63;
    if (wid >= N_NODES) return;
    const int dst = wid;
    const int hh = lane >> 4, sub = lane & 15;
    const int beg = row_ptr[dst], end = row_ptr[dst + 1];
    const float edd = ed[dst * 4 + hh];
    const float self_v = lrelu(es[dst * 4 + hh] + edd);

    // pass 1: per-head max, 16 lanes per head stride edges
    float m = self_v;
    for (int k = beg + sub; k < end; k += 16)
        m = fmaxf(m, lrelu(es[csr_src[k] * 4 + hh] + edd));
    #pragma unroll
    for (int off = 1; off < 16; off <<= 1) m = fmaxf(m, __shfl_xor(m, off, 64));

    // pass 2: per-head sum of exp
    float s = 0.f;
    for (int k = beg + sub; k < end; k += 16)
        s += expf(lrelu(es[csr_src[k] * 4 + hh] + edd) - m);
    #pragma unroll
    for (int off = 1; off < 16; off <<= 1) s += __shfl_xor(s, off, 64);
    float p_self = expf(self_v - m);
    s += p_self;
    const float inv_s = 1.f / s;

    // pass 3: aggregate, whole wave walks edges once; 8 floats (32B) per lane
    const float* hd = h + (size_t)dst * 512 + lane * 8;
    float4 hd0 = *(const float4*)hd;
    float4 hd1 = *(const float4*)(hd + 4);
    const float a_self = p_self * inv_s;
    float4 acc0, acc1;
    acc0.x = a_self * hd0.x; acc0.y = a_self * hd0.y; acc0.z = a_self * hd0.z; acc0.w = a_self * hd0.w;
    acc1.x = a_self * hd1.x; acc1.y = a_self * hd1.y; acc1.z = a_self * hd1.z; acc1.w = a_self * hd1.w;

    for (int k = beg; k < end; ++k) {
        int src = csr_src[k];
        float alpha = expf(lrelu(es[src * 4 + hh] + edd) - m) * inv_s;
        const float* hs = h + (size_t)src * 512 + lane * 8;
        float4 h0 = *(const float4*)hs;
        float4 h1 = *(const float4*)(hs + 4);
        acc0.x += alpha * h0.x; acc0.y += alpha * h0.y; acc0.z += alpha * h0.z; acc0.w += alpha * h0.w;
        acc1.x += alpha * h1.x; acc1.y += alpha * h1.y; acc1.z += alpha * h1.z; acc1.w += alpha * h1.w;
    }

    // epilogue: bias + ELU
    const float* bb = b + lane * 8;
    float4 b0 = *(const float4*)bb;
    float4 b1 = *(const float4*)(bb + 4);
    float o[8] = {acc0.x + b0.x, acc0.y + b0.y, acc0.z + b0.z, acc0.w + b0.w,
                  acc1.x + b1.x, acc1.y + b1.y, acc1.z + b1.z, acc1.w + b1.w};
    #pragma unroll
    for (int j = 0; j < 8; ++j) o[j] = o[j] > 0.f ? o[j] : expm1f(o[j]);
    float* op = out + (size_t)dst * 512 + lane * 8;
    *(float4*)op = make_float4(o[0], o[1], o[2], o[3]);
    *(float4*)(op + 4) = make_float4(o[4], o[5], o[6], o[7]);
}

// ---------------- Layer 2 edge phase: wave per dst, 4 edge-groups ----------------
// lane = g*16 + sub; group g handles edge k0+g; sub covers channels sub*4..+3
__global__ void k_gat_edge_l2(const int* __restrict__ row_ptr, const int* __restrict__ csr_src,
                              const float* __restrict__ h, const float* __restrict__ es,
                              const float* __restrict__ ed, const float* __restrict__ b,
                              float* __restrict__ out) {
    int wid = (blockIdx.x * blockDim.x + threadIdx.x) >> 6;
    int lane = threadIdx.x & 63;
    if (wid >= N_NODES) return;
    const int dst = wid;
    const int g = lane >> 4, sub = lane & 15;
    const int beg = row_ptr[dst], end = row_ptr[dst + 1];
    const float edd = ed[dst];
    const float self_v = lrelu(es[dst] + edd);

    float m = self_v;
    for (int k = beg + lane; k < end; k += 64)
        m = fmaxf(m, lrelu(es[csr_src[k]] + edd));
    #pragma unroll
    for (int off = 32; off; off >>= 1) m = fmaxf(m, __shfl_xor(m, off, 64));

    float s = 0.f;
    for (int k = beg + lane; k < end; k += 64)
        s += expf(lrelu(es[csr_src[k]] + edd) - m);
    #pragma unroll
    for (int off = 32; off; off >>= 1) s += __shfl_xor(s, off, 64);
    float p_self = expf(self_v - m);
    s += p_self;
    const float inv_s = 1.f / s;

    float4 acc = {0.f, 0.f, 0.f, 0.f};
    if (g == 0) {
        float4 hd = *(const float4*)&h[(size_t)dst * 64 + sub * 4];
        float a_self = p_self * inv_s;
        acc.x = a_self * hd.x; acc.y = a_self * hd.y; acc.z = a_self * hd.z; acc.w = a_self * hd.w;
    }
    for (int k0 = beg; k0 < end; k0 += 4) {
        int k = k0 + g;
        if (k < end) {
            int src = csr_src[k];
            float alpha = expf(lrelu(es[src] + edd) - m) * inv_s;
            float4 hs = *(const float4*)&h[(size_t)src * 64 + sub * 4];
            acc.x += alpha * hs.x; acc.y += alpha * hs.y; acc.z += alpha * hs.z; acc.w += alpha * hs.w;
        }
    }
    #pragma unroll
    for (int off = 16; off < 64; off <<= 1) {
        acc.x += __shfl_xor(acc.x, off, 64);
        acc.y += __shfl_xor(acc.y, off, 64);
        acc.z += __shfl_xor(acc.z, off, 64);
        acc.w += __shfl_xor(acc.w, off, 64);
    }
    if (g == 0) {
        float4 bv = *(const float4*)&b[sub * 4];
        float o[4] = {acc.x + bv.x, acc.y + bv.y, acc.z + bv.z, acc.w + bv.w};
        #pragma unroll
        for (int j = 0; j < 4; ++j) o[j] = o[j] > 0.f ? o[j] : expm1f(o[j]);
        *(float4*)&out[(size_t)dst * 64 + sub * 4] = make_float4(o[0], o[1], o[2], o[3]);
    }
}

// ---------------- layer 3 edge phase (H=1, C=1) ----------------
__global__ void k_gat_edge_c1(const int* __restrict__ row_ptr, const int* __restrict__ csr_src,
                              const float* __restrict__ h, const float* __restrict__ es,
                              const float* __restrict__ ed, float* __restrict__ out) {
    int dst = blockIdx.x * blockDim.x + threadIdx.x;
    if (dst >= N_NODES) return;
    int beg = row_ptr[dst], end = row_ptr[dst + 1];
    float edd = ed[dst];
    float self_v = lrelu(es[dst] + edd);
    float m = self_v;
    for (int k = beg; k < end; ++k) m = fmaxf(m, lrelu(es[csr_src[k]] + edd));
    float p = expf(self_v - m);
    float s = p;
    float acc = p * h[dst];
    for (int k = beg; k < end; ++k) {
        int src = csr_src[k];
        float pv = expf(lrelu(es[src] + edd) - m);
        s += pv;
        acc += pv * h[src];
    }
    out[dst] = acc / s;
}

// ---------------- final mean + b3 ----------------
__global__ void k_mean(const float* __restrict__ v, const float* __restrict__ b3,
                       float* __restrict__ out, int n) {
    __shared__ float sdata[256];
    float local = 0.f;
    for (int i = blockIdx.x * blockDim.x + threadIdx.x; i < n; i += gridDim.x * blockDim.x)
        local += v[i];
    sdata[threadIdx.x] = local;
    __syncthreads();
    for (int sft = 128; sft > 0; sft >>= 1) {
        if (threadIdx.x < sft) sdata[threadIdx.x] += sdata[threadIdx.x + sft];
        __syncthreads();
    }
    if (threadIdx.x == 0) {
        float add = sdata[0] / (float)n;
        if (blockIdx.x == 0) add += b3[0];
        atomicAdd(out, add);
    }
}

extern "C" void kernel_launch(void* const* d_in, const int* in_sizes, int n_in,
                              void* d_out, int out_size, void* d_ws, size_t ws_size,
                              hipStream_t stream) {
    const float* x      = (const float*)d_in[0];
    const float* W1     = (const float*)d_in[1];
    const float* a_src1 = (const float*)d_in[2];
    const float* a_dst1 = (const float*)d_in[3];
    const float* b1     = (const float*)d_in[4];
    const float* W2     = (const float*)d_in[5];
    const float* a_src2 = (const float*)d_in[6];
    const float* a_dst2 = (const float*)d_in[7];
    const float* b2     = (const float*)d_in[8];
    const float* W3     = (const float*)d_in[9];
    const float* a_src3 = (const float*)d_in[10];
    const float* a_dst3 = (const float*)d_in[11];
    const float* b3     = (const float*)d_in[12];
    const int*   ei     = (const int*)d_in[13];
    float* out = (float*)d_out;

    const int BS = 256;
    const size_t N = N_NODES;

    float* ws      = (float*)d_ws;
    float* h_buf   = ws;                  // N*512
    float* o_buf   = h_buf + N * 512;     // N*512
    float* es_buf  = o_buf + N * 512;     // N*4
    float* ed_buf  = es_buf + N * 4;      // N*4
    int*   deg     = (int*)(ed_buf + N * 4);
    int*   row_ptr = deg + N;
    int*   csr_src = row_ptr + N + 1;

    // CSR build (shared by all 3 layers)
    hipMemsetAsync(deg, 0, N * sizeof(int), stream);
    k_count<<<cdiv(E_EDGES, BS), BS, 0, stream>>>(ei, deg);
    k_scan<<<1, 1024, 0, stream>>>(deg, row_ptr, N_NODES);
    hipMemsetAsync(deg, 0, N * sizeof(int), stream);
    k_scatter<<<cdiv(E_EDGES, BS), BS, 0, stream>>>(ei, row_ptr, deg, csr_src);

    // Layer 1: H=4, C=128
    k_l1_gemm_coef<<<N_NODES / 16, 256, 0, stream>>>(x, W1, a_src1, a_dst1, h_buf, es_buf, ed_buf);
    k_gat_edge_l1<<<cdiv((long)N * 64, BS), BS, 0, stream>>>(row_ptr, csr_src, h_buf, es_buf, ed_buf, b1, o_buf);

    // Layer 2: H=1, C=64
    float* h2raw = h_buf;
    float* out2  = h_buf + N * 64;
    k_l2_gemm_coef<<<cdiv(N_NODES, 64), 256, 0, stream>>>(o_buf, W2, a_src2, a_dst2, h2raw, es_buf, ed_buf);
    k_gat_edge_l2<<<cdiv((long)N * 64, BS), BS, 0, stream>>>(row_ptr, csr_src, h2raw, es_buf, ed_buf, b2, out2);

    // Layer 3: H=1, C=1
    float* h3raw = h_buf + N * 128;
    float* out3  = h_buf + N * 128 + N;
    k_l3_gemm_coef<<<cdiv((long)N * 64, BS), BS, 0, stream>>>(out2, W3, a_src3, a_dst3, h3raw, es_buf, ed_buf);
    k_gat_edge_c1<<<cdiv((long)N, BS), BS, 0, stream>>>(row_ptr, csr_src, h3raw, es_buf, ed_buf, out3);

    hipMemsetAsync(out, 0, sizeof(float), stream);
    k_mean<<<256, 256, 0, stream>>>(out3, b3, out, N_NODES);
}

// Round 5
// 374.020 us; speedup vs baseline: 37.4188x; 1.1699x over previous
//
#include <hip/hip_runtime.h>
#include <hip/hip_fp16.h>
#include <math.h>

#define N_NODES 50000
#define E_EDGES 400000
#define NEG_SLOPE 0.2f

static inline int cdiv(long a, int b) { return (int)((a + b - 1) / b); }

__device__ __forceinline__ float lrelu(float v) {
    return v > 0.f ? v : NEG_SLOPE * v;
}

__device__ __forceinline__ float wave_red_sum64(float v) {
    #pragma unroll
    for (int off = 32; off; off >>= 1) v += __shfl_xor(v, off, 64);
    return v;
}

__device__ __forceinline__ void h8_to_f8(uint4 u, float o[8]) {
    union { uint4 u4; __half h[8]; } cv;
    cv.u4 = u;
    #pragma unroll
    for (int i = 0; i < 8; ++i) o[i] = __half2float(cv.h[i]);
}

__device__ __forceinline__ void h4_to_f4(uint2 u, float o[4]) {
    union { uint2 u2; __half h[4]; } cv;
    cv.u2 = u;
    #pragma unroll
    for (int i = 0; i < 4; ++i) o[i] = __half2float(cv.h[i]);
}

// ---------------- CSR build ----------------
__global__ void k_count(const int* __restrict__ ei, int* __restrict__ deg) {
    int e = blockIdx.x * blockDim.x + threadIdx.x;
    if (e >= E_EDGES) return;
    atomicAdd(&deg[ei[E_EDGES + e]], 1);
}

__global__ void k_scan(const int* __restrict__ deg, int* __restrict__ row_ptr, int n) {
    __shared__ int part[1024];
    int t = threadIdx.x;
    int chunk = (n + 1023) / 1024;
    int lo = t * chunk, hi = min(lo + chunk, n);
    int s = 0;
    for (int i = lo; i < hi; ++i) s += deg[i];
    part[t] = s;
    __syncthreads();
    for (int off = 1; off < 1024; off <<= 1) {
        int v = (t >= off) ? part[t - off] : 0;
        __syncthreads();
        part[t] += v;
        __syncthreads();
    }
    int base = (t == 0) ? 0 : part[t - 1];
    for (int i = lo; i < hi; ++i) {
        row_ptr[i] = base;
        base += deg[i];
    }
    if (t == 1023) row_ptr[n] = part[1023];
}

__global__ void k_scatter(const int* __restrict__ ei, const int* __restrict__ row_ptr,
                          int* __restrict__ pos, int* __restrict__ csr_src) {
    int e = blockIdx.x * blockDim.x + threadIdx.x;
    if (e >= E_EDGES) return;
    int src = ei[e], dst = ei[E_EDGES + e];
    int p = atomicAdd(&pos[dst], 1);
    csr_src[row_ptr[dst] + p] = src;
}

// ---------------- Layer 1: fused GEMM (x@W1) + es/ed; h stored fp16 ----------------
__global__ void k_l1_gemm_coef(const float* __restrict__ x, const float* __restrict__ W1,
                               const float* __restrict__ a_src, const float* __restrict__ a_dst,
                               __half* __restrict__ h16, float* __restrict__ es, float* __restrict__ ed) {
    const int t = threadIdx.x;
    const int lane = t & 63;
    const int hh = t >> 6;
    const int row0 = blockIdx.x * 16;
    const int c = 2 * t;

    float2 wreg[21];
    #pragma unroll
    for (int k = 0; k < 21; ++k)
        wreg[k] = *(const float2*)&W1[k * 512 + c];

    const int cih = c & 127;
    float2 as = *(const float2*)&a_src[hh * 128 + cih];
    float2 ad = *(const float2*)&a_dst[hh * 128 + cih];

    for (int r = 0; r < 16; ++r) {
        const int row = row0 + r;
        const float* xr = x + (size_t)row * 21;
        float2 acc = {0.f, 0.f};
        #pragma unroll
        for (int k = 0; k < 21; ++k) {
            float xv = xr[k];
            acc.x += xv * wreg[k].x;
            acc.y += xv * wreg[k].y;
        }
        __half2 hv;
        hv.x = __float2half_rn(acc.x);
        hv.y = __float2half_rn(acc.y);
        *(__half2*)&h16[(size_t)row * 512 + c] = hv;
        float p1 = acc.x * as.x + acc.y * as.y;
        float p2 = acc.x * ad.x + acc.y * ad.y;
        p1 = wave_red_sum64(p1);
        p2 = wave_red_sum64(p2);
        if (lane == 0) {
            es[row * 4 + hh] = p1;
            ed[row * 4 + hh] = p2;
        }
    }
}

// ---------------- Layer 2: tiled GEMM (out1@W2) + es/ed; h2 stored fp16 ----------------
__global__ void k_l2_gemm_coef(const float* __restrict__ A, const float* __restrict__ B,
                               const float* __restrict__ a_src, const float* __restrict__ a_dst,
                               __half* __restrict__ C16, float* __restrict__ es, float* __restrict__ ed) {
    __shared__ float AT[64][65];
    __shared__ float Bs[64][64];

    const int t = threadIdx.x;
    const int tr = t >> 4, tc = t & 15;
    const int row0 = blockIdx.x * 64;

    float acc[4][4];
    #pragma unroll
    for (int r = 0; r < 4; ++r)
        #pragma unroll
        for (int cc = 0; cc < 4; ++cc) acc[r][cc] = 0.f;

    for (int k0 = 0; k0 < 512; k0 += 64) {
        #pragma unroll
        for (int i = 0; i < 4; ++i) {
            int f = i * 256 + t;
            int row = f >> 4, c4 = f & 15;
            int grow = row0 + row;
            float4 v = {0.f, 0.f, 0.f, 0.f};
            if (grow < N_NODES)
                v = *(const float4*)&A[(size_t)grow * 512 + k0 + c4 * 4];
            AT[c4 * 4 + 0][row] = v.x;
            AT[c4 * 4 + 1][row] = v.y;
            AT[c4 * 4 + 2][row] = v.z;
            AT[c4 * 4 + 3][row] = v.w;
        }
        #pragma unroll
        for (int i = 0; i < 4; ++i) {
            int f = i * 256 + t;
            int row = f >> 4, c4 = f & 15;
            *(float4*)&Bs[row][c4 * 4] = *(const float4*)&B[(size_t)(k0 + row) * 64 + c4 * 4];
        }
        __syncthreads();
        #pragma unroll 8
        for (int kk = 0; kk < 64; ++kk) {
            float4 a4 = *(const float4*)&AT[kk][tr * 4];
            float4 b4 = *(const float4*)&Bs[kk][tc * 4];
            const float av[4] = {a4.x, a4.y, a4.z, a4.w};
            const float bv[4] = {b4.x, b4.y, b4.z, b4.w};
            #pragma unroll
            for (int r = 0; r < 4; ++r)
                #pragma unroll
                for (int cc = 0; cc < 4; ++cc)
                    acc[r][cc] += av[r] * bv[cc];
        }
        __syncthreads();
    }

    float4 as4 = *(const float4*)&a_src[tc * 4];
    float4 ad4 = *(const float4*)&a_dst[tc * 4];
    #pragma unroll
    for (int r = 0; r < 4; ++r) {
        int grow = row0 + tr * 4 + r;
        float4 cv = {acc[r][0], acc[r][1], acc[r][2], acc[r][3]};
        float p1 = cv.x * as4.x + cv.y * as4.y + cv.z * as4.z + cv.w * as4.w;
        float p2 = cv.x * ad4.x + cv.y * ad4.y + cv.z * ad4.z + cv.w * ad4.w;
        #pragma unroll
        for (int off = 8; off; off >>= 1) {
            p1 += __shfl_xor(p1, off, 64);
            p2 += __shfl_xor(p2, off, 64);
        }
        if (grow < N_NODES) {
            union { uint2 u2; __half h[4]; } o;
            o.h[0] = __float2half_rn(cv.x);
            o.h[1] = __float2half_rn(cv.y);
            o.h[2] = __float2half_rn(cv.z);
            o.h[3] = __float2half_rn(cv.w);
            *(uint2*)&C16[(size_t)grow * 64 + tc * 4] = o.u2;
            if (tc == 0) { es[grow] = p1; ed[grow] = p2; }
        }
    }
}

// ---------------- Layer 3: wave-per-node dot + es/ed ----------------
__global__ void k_l3_gemm_coef(const float* __restrict__ A, const float* __restrict__ W3,
                               const float* __restrict__ a_src, const float* __restrict__ a_dst,
                               float* __restrict__ h3, float* __restrict__ es, float* __restrict__ ed) {
    int gid = blockIdx.x * blockDim.x + threadIdx.x;
    int node = gid >> 6, lane = gid & 63;
    if (node >= N_NODES) return;
    float v = A[(size_t)node * 64 + lane] * W3[lane];
    v = wave_red_sum64(v);
    if (lane == 0) {
        h3[node] = v;
        es[node] = v * a_src[0];
        ed[node] = v * a_dst[0];
    }
}

// ---------------- Layer 1 edge phase: head-fused, wave per dst, fp16 gather ----------------
__global__ void k_gat_edge_l1(const int* __restrict__ row_ptr, const int* __restrict__ csr_src,
                              const __half* __restrict__ h16, const float* __restrict__ es,
                              const float* __restrict__ ed, const float* __restrict__ b,
                              float* __restrict__ out) {
    int wid = (blockIdx.x * blockDim.x + threadIdx.x) >> 6;
    int lane = threadIdx.x & 63;
    if (wid >= N_NODES) return;
    const int dst = wid;
    const int hh = lane >> 4, sub = lane & 15;
    const int beg = row_ptr[dst], end = row_ptr[dst + 1];
    const float edd = ed[dst * 4 + hh];
    const float self_v = lrelu(es[dst * 4 + hh] + edd);

    // pass 1: per-head max
    float m = self_v;
    for (int k = beg + sub; k < end; k += 16)
        m = fmaxf(m, lrelu(es[csr_src[k] * 4 + hh] + edd));
    #pragma unroll
    for (int off = 1; off < 16; off <<= 1) m = fmaxf(m, __shfl_xor(m, off, 64));

    // pass 2: per-head sum of exp
    float s = 0.f;
    for (int k = beg + sub; k < end; k += 16)
        s += expf(lrelu(es[csr_src[k] * 4 + hh] + edd) - m);
    #pragma unroll
    for (int off = 1; off < 16; off <<= 1) s += __shfl_xor(s, off, 64);
    float p_self = expf(self_v - m);
    s += p_self;
    const float inv_s = 1.f / s;

    // pass 3: aggregate; lane covers 8 halves (16B) of the 512-wide row
    float acc[8];
    {
        uint4 r = *(const uint4*)(h16 + (size_t)dst * 512 + lane * 8);
        float hv[8]; h8_to_f8(r, hv);
        const float a_self = p_self * inv_s;
        #pragma unroll
        for (int j = 0; j < 8; ++j) acc[j] = a_self * hv[j];
    }

    int k = beg;
    for (; k + 2 <= end; k += 2) {
        int s0 = csr_src[k], s1 = csr_src[k + 1];
        uint4 r0 = *(const uint4*)(h16 + (size_t)s0 * 512 + lane * 8);
        uint4 r1 = *(const uint4*)(h16 + (size_t)s1 * 512 + lane * 8);
        float e0 = es[s0 * 4 + hh], e1 = es[s1 * 4 + hh];
        float a0 = expf(lrelu(e0 + edd) - m) * inv_s;
        float a1 = expf(lrelu(e1 + edd) - m) * inv_s;
        float h0[8], h1[8];
        h8_to_f8(r0, h0);
        h8_to_f8(r1, h1);
        #pragma unroll
        for (int j = 0; j < 8; ++j) acc[j] += a0 * h0[j] + a1 * h1[j];
    }
    if (k < end) {
        int s0 = csr_src[k];
        uint4 r0 = *(const uint4*)(h16 + (size_t)s0 * 512 + lane * 8);
        float a0 = expf(lrelu(es[s0 * 4 + hh] + edd) - m) * inv_s;
        float h0[8]; h8_to_f8(r0, h0);
        #pragma unroll
        for (int j = 0; j < 8; ++j) acc[j] += a0 * h0[j];
    }

    // epilogue: bias + ELU
    const float* bb = b + lane * 8;
    float4 b0 = *(const float4*)bb;
    float4 b1 = *(const float4*)(bb + 4);
    float o[8] = {acc[0] + b0.x, acc[1] + b0.y, acc[2] + b0.z, acc[3] + b0.w,
                  acc[4] + b1.x, acc[5] + b1.y, acc[6] + b1.z, acc[7] + b1.w};
    #pragma unroll
    for (int j = 0; j < 8; ++j) o[j] = o[j] > 0.f ? o[j] : expm1f(o[j]);
    float* op = out + (size_t)dst * 512 + lane * 8;
    *(float4*)op = make_float4(o[0], o[1], o[2], o[3]);
    *(float4*)(op + 4) = make_float4(o[4], o[5], o[6], o[7]);
}

// ---------------- Layer 2 edge phase: wave per dst, 4 edge-groups, fp16 gather ----------------
__global__ void k_gat_edge_l2(const int* __restrict__ row_ptr, const int* __restrict__ csr_src,
                              const __half* __restrict__ h16, const float* __restrict__ es,
                              const float* __restrict__ ed, const float* __restrict__ b,
                              float* __restrict__ out) {
    int wid = (blockIdx.x * blockDim.x + threadIdx.x) >> 6;
    int lane = threadIdx.x & 63;
    if (wid >= N_NODES) return;
    const int dst = wid;
    const int g = lane >> 4, sub = lane & 15;
    const int beg = row_ptr[dst], end = row_ptr[dst + 1];
    const float edd = ed[dst];
    const float self_v = lrelu(es[dst] + edd);

    float m = self_v;
    for (int k = beg + lane; k < end; k += 64)
        m = fmaxf(m, lrelu(es[csr_src[k]] + edd));
    #pragma unroll
    for (int off = 32; off; off >>= 1) m = fmaxf(m, __shfl_xor(m, off, 64));

    float s = 0.f;
    for (int k = beg + lane; k < end; k += 64)
        s += expf(lrelu(es[csr_src[k]] + edd) - m);
    #pragma unroll
    for (int off = 32; off; off >>= 1) s += __shfl_xor(s, off, 64);
    float p_self = expf(self_v - m);
    s += p_self;
    const float inv_s = 1.f / s;

    float acc[4] = {0.f, 0.f, 0.f, 0.f};
    if (g == 0) {
        uint2 r = *(const uint2*)(h16 + (size_t)dst * 64 + sub * 4);
        float hv[4]; h4_to_f4(r, hv);
        float a_self = p_self * inv_s;
        #pragma unroll
        for (int j = 0; j < 4; ++j) acc[j] = a_self * hv[j];
    }
    for (int k0 = beg; k0 < end; k0 += 4) {
        int k = k0 + g;
        if (k < end) {
            int src = csr_src[k];
            float alpha = expf(lrelu(es[src] + edd) - m) * inv_s;
            uint2 r = *(const uint2*)(h16 + (size_t)src * 64 + sub * 4);
            float hv[4]; h4_to_f4(r, hv);
            #pragma unroll
            for (int j = 0; j < 4; ++j) acc[j] += alpha * hv[j];
        }
    }
    #pragma unroll
    for (int off = 16; off < 64; off <<= 1) {
        #pragma unroll
        for (int j = 0; j < 4; ++j) acc[j] += __shfl_xor(acc[j], off, 64);
    }
    if (g == 0) {
        float4 bv = *(const float4*)&b[sub * 4];
        float o[4] = {acc[0] + bv.x, acc[1] + bv.y, acc[2] + bv.z, acc[3] + bv.w};
        #pragma unroll
        for (int j = 0; j < 4; ++j) o[j] = o[j] > 0.f ? o[j] : expm1f(o[j]);
        *(float4*)&out[(size_t)dst * 64 + sub * 4] = make_float4(o[0], o[1], o[2], o[3]);
    }
}

// ---------------- layer 3 edge phase (H=1, C=1) ----------------
__global__ void k_gat_edge_c1(const int* __restrict__ row_ptr, const int* __restrict__ csr_src,
                              const float* __restrict__ h, const float* __restrict__ es,
                              const float* __restrict__ ed, float* __restrict__ out) {
    int dst = blockIdx.x * blockDim.x + threadIdx.x;
    if (dst >= N_NODES) return;
    int beg = row_ptr[dst], end = row_ptr[dst + 1];
    float edd = ed[dst];
    float self_v = lrelu(es[dst] + edd);
    float m = self_v;
    for (int k = beg; k < end; ++k) m = fmaxf(m, lrelu(es[csr_src[k]] + edd));
    float p = expf(self_v - m);
    float s = p;
    float acc = p * h[dst];
    for (int k = beg; k < end; ++k) {
        int src = csr_src[k];
        float pv = expf(lrelu(es[src] + edd) - m);
        s += pv;
        acc += pv * h[src];
    }
    out[dst] = acc / s;
}

// ---------------- final mean + b3 ----------------
__global__ void k_mean(const float* __restrict__ v, const float* __restrict__ b3,
                       float* __restrict__ out, int n) {
    __shared__ float sdata[256];
    float local = 0.f;
    for (int i = blockIdx.x * blockDim.x + threadIdx.x; i < n; i += gridDim.x * blockDim.x)
        local += v[i];
    sdata[threadIdx.x] = local;
    __syncthreads();
    for (int sft = 128; sft > 0; sft >>= 1) {
        if (threadIdx.x < sft) sdata[threadIdx.x] += sdata[threadIdx.x + sft];
        __syncthreads();
    }
    if (threadIdx.x == 0) {
        float add = sdata[0] / (float)n;
        if (blockIdx.x == 0) add += b3[0];
        atomicAdd(out, add);
    }
}

extern "C" void kernel_launch(void* const* d_in, const int* in_sizes, int n_in,
                              void* d_out, int out_size, void* d_ws, size_t ws_size,
                              hipStream_t stream) {
    const float* x      = (const float*)d_in[0];
    const float* W1     = (const float*)d_in[1];
    const float* a_src1 = (const float*)d_in[2];
    const float* a_dst1 = (const float*)d_in[3];
    const float* b1     = (const float*)d_in[4];
    const float* W2     = (const float*)d_in[5];
    const float* a_src2 = (const float*)d_in[6];
    const float* a_dst2 = (const float*)d_in[7];
    const float* b2     = (const float*)d_in[8];
    const float* W3     = (const float*)d_in[9];
    const float* a_src3 = (const float*)d_in[10];
    const float* a_dst3 = (const float*)d_in[11];
    const float* b3     = (const float*)d_in[12];
    const int*   ei     = (const int*)d_in[13];
    float* out = (float*)d_out;

    const int BS = 256;
    const size_t N = N_NODES;

    // workspace layout (float units)
    float*  ws      = (float*)d_ws;
    __half* h16     = (__half*)ws;                 // N*512 halves = N*256 floats
    float*  o_buf   = ws + N * 256;                // N*512 floats (out1, f32)
    __half* h2_16   = (__half*)(o_buf + N * 512);  // N*64 halves = N*32 floats
    float*  out2    = o_buf + N * 512 + N * 32;    // N*64
    float*  h3raw   = out2 + N * 64;               // N
    float*  out3    = h3raw + N;                   // N
    float*  es_buf  = out3 + N;                    // N*4
    float*  ed_buf  = es_buf + N * 4;              // N*4
    int*    deg     = (int*)(ed_buf + N * 4);      // N
    int*    row_ptr = deg + N;                     // N+1
    int*    csr_src = row_ptr + N + 1;             // E_EDGES

    // CSR build (shared by all 3 layers)
    hipMemsetAsync(deg, 0, N * sizeof(int), stream);
    k_count<<<cdiv(E_EDGES, BS), BS, 0, stream>>>(ei, deg);
    k_scan<<<1, 1024, 0, stream>>>(deg, row_ptr, N_NODES);
    hipMemsetAsync(deg, 0, N * sizeof(int), stream);
    k_scatter<<<cdiv(E_EDGES, BS), BS, 0, stream>>>(ei, row_ptr, deg, csr_src);

    // Layer 1: H=4, C=128
    k_l1_gemm_coef<<<N_NODES / 16, 256, 0, stream>>>(x, W1, a_src1, a_dst1, h16, es_buf, ed_buf);
    k_gat_edge_l1<<<cdiv((long)N * 64, BS), BS, 0, stream>>>(row_ptr, csr_src, h16, es_buf, ed_buf, b1, o_buf);

    // Layer 2: H=1, C=64
    k_l2_gemm_coef<<<cdiv(N_NODES, 64), 256, 0, stream>>>(o_buf, W2, a_src2, a_dst2, h2_16, es_buf, ed_buf);
    k_gat_edge_l2<<<cdiv((long)N * 64, BS), BS, 0, stream>>>(row_ptr, csr_src, h2_16, es_buf, ed_buf, b2, out2);

    // Layer 3: H=1, C=1
    k_l3_gemm_coef<<<cdiv((long)N * 64, BS), BS, 0, stream>>>(out2, W3, a_src3, a_dst3, h3raw, es_buf, ed_buf);
    k_gat_edge_c1<<<cdiv((long)N, BS), BS, 0, stream>>>(row_ptr, csr_src, h3raw, es_buf, ed_buf, out3);

    hipMemsetAsync(out, 0, sizeof(float), stream);
    k_mean<<<256, 256, 0, stream>>>(out3, b3, out, N_NODES);
}